// Round 5
// baseline (420.555 us; speedup 1.0000x reference)
//
#include <hip/hip_runtime.h>
#include <math.h>

#define C 64
#define D 16
#define EPSF 1e-8f
#define DVAR 0.5f
#define DDIST 1.5f
#define FPSCALE 65536.0f
#define INV_FPSCALE (1.0f / 65536.0f)
#define VARSCALE 4294967296.0
#define INV_VARSCALE (1.0 / 4294967296.0)
#define BIAS 524288  // 2^19 > max |round(f*65536)| for |f|<8; keeps packed halves carry-free

#define NB 2048        // 8 blocks/CU x 256 CUs
#define NTHR (NB * 256) // 524288 = 1<<19
#define SLICE 1088     // per-block private histogram: 1024 sums + 64 counts

// ws int32 layout (nothing needs pre-zeroing; everything is written before read):
//   [0 .. NB*SLICE)            per-block slices, arr[b][0..1087]
//   [GF0 .. GF0+1088)          reduced g_sums[1024] + g_cnt[64]
//   [V0 .. V0+2*NB)            per-block var partials, u64 fixed-point (V0 even -> 8B-aligned)
#define GF0 (NB * SLICE)
#define V0 (GF0 + 1088)

__device__ __forceinline__ unsigned long long pack2(float x, float y) {
    // two biased fixed-point components in one u64; bias keeps each half non-negative
    unsigned lo = (unsigned)(__float2int_rn(x * FPSCALE) + BIAS);
    unsigned hi = (unsigned)(__float2int_rn(y * FPSCALE) + BIAS);
    return ((unsigned long long)hi << 32) | (unsigned long long)lo;
}

__global__ __launch_bounds__(256) void k_sums(const float4* __restrict__ f4,
                                              const int* __restrict__ labels, int N,
                                              int* __restrict__ arr) {
    // u64-packed LDS histogram: 8 ds_add_u64 + 1 ds_add_u32 per point (was 17 u32 RMWs).
    // REVERSE tile order: ends on the array head so k_hinge (forward) hits L3.
    __shared__ unsigned long long s_sum2[C * 9];  // 8 packed pairs + 1 pad (stride 72B)
    __shared__ unsigned s_cnt[C];
    int t = threadIdx.x;
    int b = blockIdx.x;
    for (int i = t; i < C * 9; i += 256) s_sum2[i] = 0ull;
    if (t < C) s_cnt[t] = 0u;
    __syncthreads();

    int nfull = N >> 8;          // full 256-point tiles; body below is branch-free
    for (int it = b; it < nfull; it += NB) {
        int tile = nfull - 1 - it;
        int p = (tile << 8) + t;
        int c = labels[p] & (C - 1);
        float4 a  = f4[4 * p + 0];
        float4 bb = f4[4 * p + 1];
        float4 cc = f4[4 * p + 2];
        float4 dd = f4[4 * p + 3];
        unsigned long long* row = &s_sum2[c * 9];
        atomicAdd(row + 0, pack2(a.x,  a.y));
        atomicAdd(row + 1, pack2(a.z,  a.w));
        atomicAdd(row + 2, pack2(bb.x, bb.y));
        atomicAdd(row + 3, pack2(bb.z, bb.w));
        atomicAdd(row + 4, pack2(cc.x, cc.y));
        atomicAdd(row + 5, pack2(cc.z, cc.w));
        atomicAdd(row + 6, pack2(dd.x, dd.y));
        atomicAdd(row + 7, pack2(dd.z, dd.w));
        atomicAdd(&s_cnt[c], 1u);
    }
    // tail points (N % 256), handled once by block 0
    int tail = N & 255;
    if (tail && b == 0 && t < tail) {
        int p = (nfull << 8) + t;
        int c = labels[p] & (C - 1);
        float4 a  = f4[4 * p + 0];
        float4 bb = f4[4 * p + 1];
        float4 cc = f4[4 * p + 2];
        float4 dd = f4[4 * p + 3];
        unsigned long long* row = &s_sum2[c * 9];
        atomicAdd(row + 0, pack2(a.x,  a.y));
        atomicAdd(row + 1, pack2(a.z,  a.w));
        atomicAdd(row + 2, pack2(bb.x, bb.y));
        atomicAdd(row + 3, pack2(bb.z, bb.w));
        atomicAdd(row + 4, pack2(cc.x, cc.y));
        atomicAdd(row + 5, pack2(cc.z, cc.w));
        atomicAdd(row + 6, pack2(dd.x, dd.y));
        atomicAdd(row + 7, pack2(dd.z, dd.w));
        atomicAdd(&s_cnt[c], 1u);
    }
    __syncthreads();
    // flush: un-bias (half - cnt*2^19, modular-exact int32) -> same slice format as before
    for (int i = t; i < SLICE; i += 256) {
        int v;
        if (i < C * D) {
            int c = i >> 4, d = i & 15;
            unsigned long long w = s_sum2[c * 9 + (d >> 1)];
            unsigned half = (d & 1) ? (unsigned)(w >> 32) : (unsigned)w;
            v = (int)(half - (s_cnt[c] << 19));
        } else {
            v = (int)s_cnt[i - C * D];
        }
        arr[b * SLICE + i] = v;
    }
}

// Column-sum of the NB x SLICE slice matrix. int add == atomic result, bit-exact.
__global__ __launch_bounds__(256) void k_reduce(const int* __restrict__ arr,
                                                int* __restrict__ g_final) {
    __shared__ int s[256];
    int o = blockIdx.x;   // 0..1087: which histogram word
    int t = threadIdx.x;
    int part = 0;
    #pragma unroll
    for (int j = 0; j < NB / 256; j++)
        part += arr[(t + j * 256) * SLICE + o];
    s[t] = part;
    __syncthreads();
    for (int st = 128; st > 0; st >>= 1) {
        if (t < st) s[t] += s[t + st];
        __syncthreads();
    }
    if (t == 0) g_final[o] = s[0];
}

__device__ __forceinline__ float point_term(const float* __restrict__ s_means,
                                            const float* __restrict__ s_w,
                                            float4 a, float4 bb, float4 cc, float4 dd,
                                            int c) {
    const float* m = &s_means[c * 20];
    float4 m0 = *(const float4*)(m + 0);
    float4 m1 = *(const float4*)(m + 4);
    float4 m2 = *(const float4*)(m + 8);
    float4 m3 = *(const float4*)(m + 12);
    float ss = 0.0f, dx;
    dx = a.x - m0.x + EPSF; ss += dx * dx;
    dx = a.y - m0.y + EPSF; ss += dx * dx;
    dx = a.z - m0.z + EPSF; ss += dx * dx;
    dx = a.w - m0.w + EPSF; ss += dx * dx;
    dx = bb.x - m1.x + EPSF; ss += dx * dx;
    dx = bb.y - m1.y + EPSF; ss += dx * dx;
    dx = bb.z - m1.z + EPSF; ss += dx * dx;
    dx = bb.w - m1.w + EPSF; ss += dx * dx;
    dx = cc.x - m2.x + EPSF; ss += dx * dx;
    dx = cc.y - m2.y + EPSF; ss += dx * dx;
    dx = cc.z - m2.z + EPSF; ss += dx * dx;
    dx = cc.w - m2.w + EPSF; ss += dx * dx;
    dx = dd.x - m3.x + EPSF; ss += dx * dx;
    dx = dd.y - m3.y + EPSF; ss += dx * dx;
    dx = dd.z - m3.z + EPSF; ss += dx * dx;
    dx = dd.w - m3.w + EPSF; ss += dx * dx;
    float h = fmaxf(sqrtf(ss) - DVAR, 0.0f);
    return h * h * s_w[c];
}

__global__ __launch_bounds__(256) void k_hinge(const float4* __restrict__ f4,
                                               const int* __restrict__ labels, int N,
                                               const int* __restrict__ g_final,
                                               unsigned long long* __restrict__ g_var) {
    // forward order, consumes L3-resident head; branchless full rounds, 2x unroll for MLP.
    __shared__ __align__(16) float s_means[C * 20];
    __shared__ float s_w[C];
    __shared__ float s_red[256];
    int t = threadIdx.x;
    int b = blockIdx.x;
    for (int i = t; i < C * D; i += 256) {
        int c = i >> 4, d = i & 15;
        float cnt = fmaxf((float)g_final[C * D + c], 1.0f);
        s_means[c * 20 + d] = (float)g_final[i] * INV_FPSCALE / cnt;
    }
    if (t < C) s_w[t] = 1.0f / (fmaxf((float)g_final[C * D + t], 1.0f) * (float)C);
    __syncthreads();

    int gid = b * 256 + t;
    int rounds = N >> 19;            // NTHR == 1<<19
    int rem = N - (rounds << 19);
    float acc = 0.0f;
    int p = gid;
    // 2x-unrolled full rounds: 8 f4 loads + 2 label loads issue before any consume
    for (int r = 0; r + 2 <= rounds; r += 2) {
        int p0 = p, p1 = p + NTHR;
        int c0 = labels[p0] & (C - 1);
        int c1 = labels[p1] & (C - 1);
        float4 a0 = f4[4 * p0 + 0], b0 = f4[4 * p0 + 1],
               e0 = f4[4 * p0 + 2], d0 = f4[4 * p0 + 3];
        float4 a1 = f4[4 * p1 + 0], b1 = f4[4 * p1 + 1],
               e1 = f4[4 * p1 + 2], d1 = f4[4 * p1 + 3];
        acc += point_term(s_means, s_w, a0, b0, e0, d0, c0);
        acc += point_term(s_means, s_w, a1, b1, e1, d1, c1);
        p += 2 * NTHR;
    }
    if (rounds & 1) {
        int c0 = labels[p] & (C - 1);
        float4 a0 = f4[4 * p + 0], b0 = f4[4 * p + 1],
               e0 = f4[4 * p + 2], d0 = f4[4 * p + 3];
        acc += point_term(s_means, s_w, a0, b0, e0, d0, c0);
        p += NTHR;
    }
    if (gid < rem) {
        int c0 = labels[p] & (C - 1);
        float4 a0 = f4[4 * p + 0], b0 = f4[4 * p + 1],
               e0 = f4[4 * p + 2], d0 = f4[4 * p + 3];
        acc += point_term(s_means, s_w, a0, b0, e0, d0, c0);
    }
    s_red[t] = acc;
    __syncthreads();
    for (int s = 128; s > 0; s >>= 1) {
        if (t < s) s_red[t] += s_red[t + s];
        __syncthreads();
    }
    // plain per-block store (u64 sum is associative mod 2^64 -> bit-exact vs atomic)
    if (t == 0)
        g_var[b] = (unsigned long long)((double)s_red[0] * VARSCALE + 0.5);
}

__global__ __launch_bounds__(256) void k_final(const int* __restrict__ g_final,
                                               const unsigned long long* __restrict__ g_var,
                                               float* __restrict__ out) {
    __shared__ float s_m[C * 17];
    __shared__ float red[256];
    __shared__ unsigned long long red64[256];
    int t = threadIdx.x;
    for (int i = t; i < C * D; i += 256) {
        int c = i >> 4, d = i & 15;
        float cnt = fmaxf((float)g_final[C * D + c], 1.0f);
        s_m[c * 17 + d] = (float)g_final[i] * INV_FPSCALE / cnt;
    }
    // reduce the NB u64 var partials
    unsigned long long vq = 0ull;
    #pragma unroll
    for (int j = 0; j < NB / 256; j++) vq += g_var[t + j * 256];
    red64[t] = vq;
    __syncthreads();
    for (int s = 128; s > 0; s >>= 1) {
        if (t < s) red64[t] += red64[t + s];
        __syncthreads();
    }
    float var_loss = (float)((double)red64[0] * INV_VARSCALE);
    __syncthreads();

    // dist_loss over ordered pairs i != j
    float ds = 0.0f;
    for (int p = t; p < C * C; p += 256) {
        int i = p >> 6, j = p & 63;
        if (i != j) {
            float ss = 0.0f;
            #pragma unroll
            for (int d = 0; d < D; d++) {
                float df = s_m[i * 17 + d] - s_m[j * 17 + d] + EPSF;
                ss += df * df;
            }
            float h = fmaxf(2.0f * DDIST - sqrtf(ss), 0.0f);
            ds += h * h;
        }
    }
    red[t] = ds;
    __syncthreads();
    for (int s = 128; s > 0; s >>= 1) {
        if (t < s) red[t] += red[t + s];
        __syncthreads();
    }
    float dist_loss = red[0] / (float)(C * (C - 1));
    __syncthreads();

    // reg_loss = mean_c ||m_c + EPS||
    float rg = 0.0f;
    if (t < C) {
        float ss = 0.0f;
        #pragma unroll
        for (int d = 0; d < D; d++) {
            float m = s_m[t * 17 + d] + EPSF;
            ss += m * m;
        }
        rg = sqrtf(ss);
    }
    red[t] = rg;
    __syncthreads();
    for (int s = 128; s > 0; s >>= 1) {
        if (t < s) red[t] += red[t + s];
        __syncthreads();
    }
    float reg_loss = red[0] / (float)C;

    if (t == 0) {
        out[0] = var_loss + dist_loss + 0.001f * reg_loss;
        out[1] = var_loss;
        out[2] = dist_loss;
        out[3] = reg_loss;
    }
}

extern "C" void kernel_launch(void* const* d_in, const int* in_sizes, int n_in,
                              void* d_out, int out_size, void* d_ws, size_t ws_size,
                              hipStream_t stream) {
    const float4* f4 = (const float4*)d_in[0];
    const int* labels = (const int*)d_in[1];
    int N = in_sizes[0] / D;

    int* ws = (int*)d_ws;
    int* arr = ws;                                                // NB*1088 ints
    int* g_final = ws + GF0;                                      // 1024 sums + 64 counts
    unsigned long long* g_var = (unsigned long long*)(ws + V0);   // NB u64 partials
    float* out = (float*)d_out;

    hipLaunchKernelGGL(k_sums, dim3(NB), dim3(256), 0, stream, f4, labels, N, arr);
    hipLaunchKernelGGL(k_reduce, dim3(SLICE), dim3(256), 0, stream, arr, g_final);
    hipLaunchKernelGGL(k_hinge, dim3(NB), dim3(256), 0, stream, f4, labels, N, g_final, g_var);
    hipLaunchKernelGGL(k_final, dim3(1), dim3(256), 0, stream, g_final, g_var, out);
}